// Round 18
// baseline (620.634 us; speedup 1.0000x reference)
//
#include <hip/hip_runtime.h>
#include <hip/hip_bf16.h>

typedef __bf16 bf16;
typedef __bf16 bf16x8 __attribute__((ext_vector_type(8)));
typedef __bf16 bf16x4 __attribute__((ext_vector_type(4)));
typedef __bf16 bf16x2 __attribute__((ext_vector_type(2)));
typedef float f32x4 __attribute__((ext_vector_type(4)));

// B=16, H=W=56, C=512, HEADS=16, hd=32, WS=7, SHIFT=3, N=49, NW=64
#define M_TOK 50176

#define GLD16(dst, src) __builtin_amdgcn_global_load_lds( \
    (const __attribute__((address_space(1))) void*)(src), \
    (__attribute__((address_space(3))) void*)(dst), 16, 0, 0)

// ---------------- weight fp32 -> bf16 conversion (4 segments, packed dst)
__global__ __launch_bounds__(256) void convert_w_kernel(
    const float* __restrict__ w0, const float* __restrict__ w1,
    const float* __restrict__ w2, const float* __restrict__ w3,
    bf16* __restrict__ dst)
{
    int blk = blockIdx.x;
    const float* src; size_t srel, drel;
    if (blk < 768)       { src = w0; srel = (size_t)blk * 1024;          drel = srel; }
    else if (blk < 1024) { src = w1; srel = (size_t)(blk - 768) * 1024;  drel = 786432 + srel; }
    else if (blk < 2048) { src = w2; srel = (size_t)(blk - 1024) * 1024; drel = 1048576 + srel; }
    else                 { src = w3; srel = (size_t)(blk - 2048) * 1024; drel = 2097152 + srel; }
    int i = threadIdx.x * 4;
    float4 v = *(const float4*)(src + srel + i);
    bf16* d = dst + drel + i;
    d[0] = (bf16)v.x; d[1] = (bf16)v.y; d[2] = (bf16)v.z; d[3] = (bf16)v.w;
}

// ---------------- bias+mask table: bt[type][head][q][64]  (k-pad = -1e9)
__global__ __launch_bounds__(64) void bias_table_kernel(
    const float* __restrict__ rpb, float* __restrict__ bt)
{
    int tq = blockIdx.x;                  // [0, 4*16*49)
    int type = tq / 784, r = tq - type * 784;
    int head = r / 49, q = r - head * 49;
    int k = threadIdx.x;
    float v;
    if (k < 49) {
        int yq = q / 7, xq = q - yq * 7;
        int yk = k / 7, xk = k - yk * 7;
        int ridx = (yq - yk + 6) * 13 + (xq - xk + 6);
        v = rpb[ridx * 16 + head];
        int th = type >> 1, tw = type & 1;
        int qid = 3 * (th ? (yq < 4 ? 1 : 2) : 0) + (tw ? (xq < 4 ? 1 : 2) : 0);
        int kid = 3 * (th ? (yk < 4 ? 1 : 2) : 0) + (tw ? (xk < 4 ? 1 : 2) : 0);
        if (qid != kid) v -= 100.f;
    } else {
        v = -1e9f;
    }
    bt[(size_t)tq * 64 + k] = v;
}

// ---------------- LN1 + cyclic shift + window partition -> h (window-token order, bf16)
__global__ __launch_bounds__(256) void ln1_window_kernel(
    const float* __restrict__ x, const float* __restrict__ g, const float* __restrict__ bta,
    bf16* __restrict__ h)
{
    int t = blockIdx.x;                 // window-token index
    int win = t / 49, n = t - win * 49;
    int bi = win >> 6, nw = win & 63;
    int wh = nw >> 3, ww = nw & 7;
    int ny = n / 7, nx = n - ny * 7;
    int r = wh * 7 + ny + 3; if (r >= 56) r -= 56;   // roll(-3)
    int c = ww * 7 + nx + 3; if (c >= 56) c -= 56;
    const float* xr = x + ((size_t)bi * 3136 + r * 56 + c) * 512;
    int tid = threadIdx.x;
    float v0 = xr[tid];
    float v1 = xr[tid + 256];
    float s = v0 + v1, ss = v0 * v0 + v1 * v1;
#pragma unroll
    for (int o = 32; o; o >>= 1) { s += __shfl_down(s, o, 64); ss += __shfl_down(ss, o, 64); }
    __shared__ float red[8];
    int wave = tid >> 6, lane = tid & 63;
    if (lane == 0) { red[wave] = s; red[4 + wave] = ss; }
    __syncthreads();
    float S = red[0] + red[1] + red[2] + red[3];
    float SS = red[4] + red[5] + red[6] + red[7];
    float mean = S * (1.f / 512.f);
    float var = SS * (1.f / 512.f) - mean * mean;
    float rstd = rsqrtf(var + 1e-5f);
    bf16* hr = h + (size_t)t * 512;
    hr[tid] = (bf16)((v0 - mean) * rstd * g[tid] + bta[tid]);
    hr[tid + 256] = (bf16)((v1 - mean) * rstd * g[tid + 256] + bta[tid + 256]);
}

// ---------------- LN2 (natural token order), x1 (fp32 or bf16) -> bf16 out
template <int X1BF>
__global__ __launch_bounds__(256) void ln2_kernel(
    const void* __restrict__ x1, const float* __restrict__ g,
    const float* __restrict__ bta, bf16* __restrict__ outp)
{
    int t = blockIdx.x;
    int tid = threadIdx.x;
    float v0, v1;
    if constexpr (X1BF) {
        const bf16* xr = (const bf16*)x1 + (size_t)t * 512;
        v0 = (float)xr[tid]; v1 = (float)xr[tid + 256];
    } else {
        const float* xr = (const float*)x1 + (size_t)t * 512;
        v0 = xr[tid]; v1 = xr[tid + 256];
    }
    float s = v0 + v1, ss = v0 * v0 + v1 * v1;
#pragma unroll
    for (int o = 32; o; o >>= 1) { s += __shfl_down(s, o, 64); ss += __shfl_down(ss, o, 64); }
    __shared__ float red[8];
    int wave = tid >> 6, lane = tid & 63;
    if (lane == 0) { red[wave] = s; red[4 + wave] = ss; }
    __syncthreads();
    float S = red[0] + red[1] + red[2] + red[3];
    float SS = red[4] + red[5] + red[6] + red[7];
    float mean = S * (1.f / 512.f);
    float var = SS * (1.f / 512.f) - mean * mean;
    float rstd = rsqrtf(var + 1e-5f);
    bf16* hr = outp + (size_t)t * 512;
    hr[tid] = (bf16)((v0 - mean) * rstd * g[tid] + bta[tid]);
    hr[tid + 256] = (bf16)((v1 - mean) * rstd * g[tid + 256] + bta[tid + 256]);
}

// ---------------- 256x128 MFMA GEMM, BK=64 single-buffer, C^T registers.
// r8/r12 loop discipline exactly; 8 waves (4M x 2N), each wave 64x64 out (32 MFMAs/tile,
// same as r8) but per-thread staging drops 8->6 GLD16 and LDS=48KB -> 3 blocks/CU
// (24 waves/CU vs r8's 16): more TLP at equal per-wave compute-per-drain.
template <int MODE, int K, int X1BF>
__global__ __launch_bounds__(512, 4) void gemm256x128_kernel(
    const bf16* __restrict__ A, const bf16* __restrict__ Wt, const float* __restrict__ bias,
    void* __restrict__ outp, const void* __restrict__ extra, int N)
{
    __shared__ bf16 As[256][64];
    __shared__ bf16 Ws[128][64];
    constexpr int NT = K / 64;
    int gx = gridDim.x;
    int lin = blockIdx.y * gx + blockIdx.x;
    int q8 = (gx * gridDim.y) >> 3;          // grids divisible by 8
    int lin2 = (lin & 7) * q8 + (lin >> 3);
    int bn = lin2 % gx, bm = lin2 / gx;
    int tid = threadIdx.x;
    int w = tid >> 6, lane = tid & 63;
    int wm = w >> 1, wn = w & 1;              // 4M x 2N waves, each 64x64 out
    int fr = lane & 15, fq = lane >> 4;
    int srow = lane >> 3;                     // 0..7 within 8-row chunk
    int scol = ((lane & 7) ^ srow) * 8;       // pre-swizzled source slot
    const bf16* gA = A + (size_t)(bm * 256 + w * 32 + srow) * K + scol;
    const bf16* gB = Wt + (size_t)(bn * 128 + w * 16 + srow) * K + scol;

    f32x4 acc[4][4];
    f32x4 z = {0.f, 0.f, 0.f, 0.f};
#pragma unroll
    for (int mf = 0; mf < 4; mf++)
#pragma unroll
        for (int nf = 0; nf < 4; nf++) acc[mf][nf] = z;

    for (int kt = 0; kt < NT; ++kt) {
        if (kt) {
            asm volatile("s_waitcnt lgkmcnt(0)" ::: "memory");
            asm volatile("s_barrier" ::: "memory");      // readers of prev tile done
        }
#pragma unroll
        for (int i = 0; i < 4; i++)
            GLD16(&As[w * 32 + i * 8][0], gA + (size_t)(i * 8) * K + kt * 64);
#pragma unroll
        for (int i = 0; i < 2; i++)
            GLD16(&Ws[w * 16 + i * 8][0], gB + (size_t)(i * 8) * K + kt * 64);
        asm volatile("s_waitcnt vmcnt(0)" ::: "memory");
        asm volatile("s_barrier" ::: "memory");
#pragma unroll
        for (int kh = 0; kh < 2; kh++) {
            bf16x8 aF[4], bF[4];
            int c = kh * 4 + fq;
#pragma unroll
            for (int f = 0; f < 4; f++) {
                aF[f] = *(const bf16x8*)&As[wm * 64 + f * 16 + fr][(c ^ (fr & 7)) * 8];
                bF[f] = *(const bf16x8*)&Ws[wn * 64 + f * 16 + fr][(c ^ (fr & 7)) * 8];
            }
#pragma unroll
            for (int mf = 0; mf < 4; mf++)
#pragma unroll
                for (int nf = 0; nf < 4; nf++)
                    acc[mf][nf] = __builtin_amdgcn_mfma_f32_16x16x32_bf16(bF[nf], aF[mf], acc[mf][nf], 0, 0, 0);
        }
    }

    // epilogue: per (mf, nf) one vector of 4 consecutive cols at row (..+fr)
#pragma unroll
    for (int mf = 0; mf < 4; mf++) {
        int row = bm * 256 + wm * 64 + mf * 16 + fr;
        size_t rowbase;
        if constexpr (MODE == 2) {
            int win = row / 49, n = row - win * 49;
            int bi = win >> 6, nw = win & 63;
            int wh = nw >> 3, wwi = nw & 7;
            int ny = n / 7, nx = n - ny * 7;
            int rr = wh * 7 + ny + 3; if (rr >= 56) rr -= 56;
            int cc = wwi * 7 + nx + 3; if (cc >= 56) cc -= 56;
            rowbase = ((size_t)bi * 3136 + rr * 56 + cc) * 512;
        } else {
            rowbase = (size_t)row * (MODE == 3 ? 512 : N);
        }
#pragma unroll
        for (int nf = 0; nf < 4; nf++) {
            int colb = bn * 128 + wn * 64 + nf * 16 + fq * 4;
            float4 b4 = *(const float4*)(bias + colb);
            float v0 = acc[mf][nf][0] + b4.x;
            float v1 = acc[mf][nf][1] + b4.y;
            float v2 = acc[mf][nf][2] + b4.z;
            float v3 = acc[mf][nf][3] + b4.w;
            size_t dst = rowbase + colb;
            if constexpr (MODE == 0) {
                bf16x4 t = {(bf16)v0, (bf16)v1, (bf16)v2, (bf16)v3};
                *(bf16x4*)((bf16*)outp + dst) = t;
            } else if constexpr (MODE == 1) {
                v0 = 0.5f * v0 * (1.f + erff(v0 * 0.70710678118654752f));
                v1 = 0.5f * v1 * (1.f + erff(v1 * 0.70710678118654752f));
                v2 = 0.5f * v2 * (1.f + erff(v2 * 0.70710678118654752f));
                v3 = 0.5f * v3 * (1.f + erff(v3 * 0.70710678118654752f));
                bf16x4 t = {(bf16)v0, (bf16)v1, (bf16)v2, (bf16)v3};
                *(bf16x4*)((bf16*)outp + dst) = t;
            } else if constexpr (MODE == 2) {
                float4 e = *(const float4*)((const float*)extra + dst);
                v0 += e.x; v1 += e.y; v2 += e.z; v3 += e.w;
                if constexpr (X1BF) {
                    bf16x4 t = {(bf16)v0, (bf16)v1, (bf16)v2, (bf16)v3};
                    *(bf16x4*)((bf16*)outp + dst) = t;
                } else {
                    float4 t = {v0, v1, v2, v3};
                    *(float4*)((float*)outp + dst) = t;
                }
            } else {
                if constexpr (X1BF) {
                    bf16x4 e = *(const bf16x4*)((const bf16*)extra + dst);
                    v0 += (float)e[0]; v1 += (float)e[1]; v2 += (float)e[2]; v3 += (float)e[3];
                } else {
                    float4 e = *(const float4*)((const float*)extra + dst);
                    v0 += e.x; v1 += e.y; v2 += e.z; v3 += e.w;
                }
                float4 t = {v0, v1, v2, v3};
                *(float4*)((float*)outp + dst) = t;
            }
        }
    }
}

// ---------------- MFMA attention: one wave per (window, head). N=49 (pad 64), hd=32.
// Independent 1-wave blocks -> setprio(1) around MFMA clusters (m191 regime).
__global__ __launch_bounds__(64) void attn_mfma_kernel(
    const bf16* __restrict__ qkv, const float* __restrict__ bt, bf16* __restrict__ outp)
{
    int wid0 = blockIdx.x;
    int wid = (wid0 & 7) * 2048 + (wid0 >> 3);   // XCD-contiguous windows
    int win = wid >> 4, head = wid & 15;
    int nw = win & 63;
    int type = ((nw >> 3) == 7 ? 2 : 0) + ((nw & 7) == 7 ? 1 : 0);
    int lane = threadIdx.x;
    int fr = lane & 15, fq = lane >> 4;
    __shared__ bf16 Vt[32][72];
    __shared__ bf16 Ps[64][72];
    const bf16* base = qkv + (size_t)win * 49 * 1536;

    uint4 z4 = {0, 0, 0, 0};
#pragma unroll
    for (int c = lane; c < 288; c += 64) ((uint4*)Vt)[c] = z4;
    __syncthreads();
    for (int c = lane; c < 1568; c += 64) {
        int tok = c >> 5, d = c & 31;
        Vt[d][tok] = base[(size_t)tok * 1536 + 1024 + head * 32 + d];
    }
    bf16x8 qf[4], kf[4];
#pragma unroll
    for (int i = 0; i < 4; i++) {
        int tq = i * 16 + fr; if (tq > 48) tq = 48;
        qf[i] = *(const bf16x8*)(base + (size_t)tq * 1536 + head * 32 + fq * 8);
        kf[i] = *(const bf16x8*)(base + (size_t)tq * 1536 + 512 + head * 32 + fq * 8);
    }
    f32x4 z = {0.f, 0.f, 0.f, 0.f};
    f32x4 st[4][4];
    __builtin_amdgcn_s_setprio(1);
#pragma unroll
    for (int mi = 0; mi < 4; mi++)
#pragma unroll
        for (int ni = 0; ni < 4; ni++)
            st[mi][ni] = __builtin_amdgcn_mfma_f32_16x16x32_bf16(kf[mi], qf[ni], z, 0, 0, 0);
    __builtin_amdgcn_s_setprio(0);
    __syncthreads();

    const float* btb = bt + (size_t)(type * 16 + head) * 49 * 64;
    float p[4][4][4];
    float inv[4];
#pragma unroll
    for (int ni = 0; ni < 4; ni++) {
        int q = ni * 16 + fr; if (q > 48) q = 48;
        const float* btr = btb + q * 64;
        float m = -1e30f;
#pragma unroll
        for (int mi = 0; mi < 4; mi++) {
            float4 bv = *(const float4*)(btr + mi * 16 + fq * 4);
#pragma unroll
            for (int r = 0; r < 4; r++) {
                float s = st[mi][ni][r] * 0.17677669529663689f + (&bv.x)[r];
                p[mi][ni][r] = s;
                m = fmaxf(m, s);
            }
        }
        m = fmaxf(m, __shfl_xor(m, 16));
        m = fmaxf(m, __shfl_xor(m, 32));
        float sum = 0.f;
#pragma unroll
        for (int mi = 0; mi < 4; mi++)
#pragma unroll
            for (int r = 0; r < 4; r++) {
                float e = __expf(p[mi][ni][r] - m);
                p[mi][ni][r] = e;
                sum += e;
            }
        sum += __shfl_xor(sum, 16);
        sum += __shfl_xor(sum, 32);
        inv[ni] = 1.f / sum;
    }
#pragma unroll
    for (int mi = 0; mi < 4; mi++)
#pragma unroll
        for (int ni = 0; ni < 4; ni++) {
            bf16x4 t;
            t[0] = (bf16)p[mi][ni][0]; t[1] = (bf16)p[mi][ni][1];
            t[2] = (bf16)p[mi][ni][2]; t[3] = (bf16)p[mi][ni][3];
            *(bf16x4*)&Ps[ni * 16 + fr][mi * 16 + fq * 4] = t;
        }
    __syncthreads();
    f32x4 o[2][4];
#pragma unroll
    for (int mi = 0; mi < 2; mi++)
#pragma unroll
        for (int ni = 0; ni < 4; ni++) o[mi][ni] = z;
    __builtin_amdgcn_s_setprio(1);
#pragma unroll
    for (int kt = 0; kt < 2; kt++) {
        bf16x8 a0 = *(const bf16x8*)&Vt[fr][kt * 32 + fq * 8];
        bf16x8 a1 = *(const bf16x8*)&Vt[16 + fr][kt * 32 + fq * 8];
#pragma unroll
        for (int ni = 0; ni < 4; ni++) {
            bf16x8 b = *(const bf16x8*)&Ps[ni * 16 + fr][kt * 32 + fq * 8];
            o[0][ni] = __builtin_amdgcn_mfma_f32_16x16x32_bf16(a0, b, o[0][ni], 0, 0, 0);
            o[1][ni] = __builtin_amdgcn_mfma_f32_16x16x32_bf16(a1, b, o[1][ni], 0, 0, 0);
        }
    }
    __builtin_amdgcn_s_setprio(0);
#pragma unroll
    for (int ni = 0; ni < 4; ni++) {
        int q = ni * 16 + fr;
        if (q < 49) {
            bf16* orow = outp + (size_t)(win * 49 + q) * 512 + head * 32;
#pragma unroll
            for (int mi = 0; mi < 2; mi++)
#pragma unroll
                for (int r2 = 0; r2 < 2; r2++) {
                    bf16x2 t;
                    t[0] = (bf16)(o[mi][ni][2 * r2] * inv[ni]);
                    t[1] = (bf16)(o[mi][ni][2 * r2 + 1] * inv[ni]);
                    *(bf16x2*)(orow + mi * 16 + fq * 4 + 2 * r2) = t;
                }
        }
    }
}

extern "C" void kernel_launch(void* const* d_in, const int* in_sizes, int n_in,
                              void* d_out, int out_size, void* d_ws, size_t ws_size,
                              hipStream_t stream)
{
    const float* x      = (const float*)d_in[0];
    const float* n1g    = (const float*)d_in[1];
    const float* n1b    = (const float*)d_in[2];
    const float* qkv_w  = (const float*)d_in[3];
    const float* qkv_b  = (const float*)d_in[4];
    const float* proj_w = (const float*)d_in[5];
    const float* proj_b = (const float*)d_in[6];
    const float* rpb    = (const float*)d_in[7];
    const float* n2g    = (const float*)d_in[8];
    const float* n2b    = (const float*)d_in[9];
    const float* fc1_w  = (const float*)d_in[10];
    const float* fc1_b  = (const float*)d_in[11];
    const float* fc2_w  = (const float*)d_in[12];
    const float* fc2_b  = (const float*)d_in[13];

    char* ws = (char*)d_ws;
    // layout (bytes):
    //   [0, 154140672)            qkv bf16                       } hid (50176x2048 bf16)
    //   [154140672, 205520896)    h bf16 -> bt fp32 after qkvGEMM}   overlays
    //   [205520896, 256901120)    attn_out bf16 -> ln2h bf16
    //   [256901120, 263192576)    weights bf16
    //   [263192576, 314572800)    x1 bf16 (only if ws_size permits)
    bf16* qkv  = (bf16*)ws;
    bf16* h    = (bf16*)(ws + 154140672ull);
    float* bt  = (float*)(ws + 154140672ull);
    bf16* ao   = (bf16*)(ws + 205520896ull);
    bf16* wbuf = (bf16*)(ws + 256901120ull);
    bf16* hid  = (bf16*)ws;
    bf16* ln2h = ao;
    bf16* wq  = wbuf;
    bf16* wp  = wbuf + 786432;
    bf16* wf1 = wbuf + 1048576;
    bf16* wf2 = wbuf + 2097152;

    bool xb = (ws_size >= 314572800ull);
    void* x1 = xb ? (void*)(ws + 263192576ull) : (void*)d_out;

    convert_w_kernel<<<3072, 256, 0, stream>>>(qkv_w, proj_w, fc1_w, fc2_w, wbuf);
    ln1_window_kernel<<<M_TOK, 256, 0, stream>>>(x, n1g, n1b, h);
    gemm256x128_kernel<0, 512, 0><<<dim3(12, 196), 512, 0, stream>>>(h, wq, qkv_b, qkv, nullptr, 1536);
    bias_table_kernel<<<3136, 64, 0, stream>>>(rpb, bt);
    attn_mfma_kernel<<<16384, 64, 0, stream>>>(qkv, bt, ao);
    if (xb) {
        gemm256x128_kernel<2, 512, 1><<<dim3(4, 196), 512, 0, stream>>>(ao, wp, proj_b, x1, x, 512);
        ln2_kernel<1><<<M_TOK, 256, 0, stream>>>(x1, n2g, n2b, ln2h);
        gemm256x128_kernel<1, 512, 1><<<dim3(16, 196), 512, 0, stream>>>(ln2h, wf1, fc1_b, hid, nullptr, 2048);
        gemm256x128_kernel<3, 2048, 1><<<dim3(4, 196), 512, 0, stream>>>(hid, wf2, fc2_b, d_out, x1, 512);
    } else {
        gemm256x128_kernel<2, 512, 0><<<dim3(4, 196), 512, 0, stream>>>(ao, wp, proj_b, x1, x, 512);
        ln2_kernel<0><<<M_TOK, 256, 0, stream>>>(x1, n2g, n2b, ln2h);
        gemm256x128_kernel<1, 512, 0><<<dim3(16, 196), 512, 0, stream>>>(ln2h, wf1, fc1_b, hid, nullptr, 2048);
        gemm256x128_kernel<3, 2048, 0><<<dim3(4, 196), 512, 0, stream>>>(hid, wf2, fc2_b, d_out, x1, 512);
    }
}

// Round 19
// 580.671 us; speedup vs baseline: 1.0688x; 1.0688x over previous
//
#include <hip/hip_runtime.h>
#include <hip/hip_bf16.h>

typedef __bf16 bf16;
typedef __bf16 bf16x8 __attribute__((ext_vector_type(8)));
typedef __bf16 bf16x4 __attribute__((ext_vector_type(4)));
typedef __bf16 bf16x2 __attribute__((ext_vector_type(2)));
typedef float f32x4 __attribute__((ext_vector_type(4)));

// B=16, H=W=56, C=512, HEADS=16, hd=32, WS=7, SHIFT=3, N=49, NW=64
#define M_TOK 50176

#define GLD16(dst, src) __builtin_amdgcn_global_load_lds( \
    (const __attribute__((address_space(1))) void*)(src), \
    (__attribute__((address_space(3))) void*)(dst), 16, 0, 0)

// ---------------- weight fp32 -> bf16 conversion (4 segments, packed dst)
__global__ __launch_bounds__(256) void convert_w_kernel(
    const float* __restrict__ w0, const float* __restrict__ w1,
    const float* __restrict__ w2, const float* __restrict__ w3,
    bf16* __restrict__ dst)
{
    int blk = blockIdx.x;
    const float* src; size_t srel, drel;
    if (blk < 768)       { src = w0; srel = (size_t)blk * 1024;          drel = srel; }
    else if (blk < 1024) { src = w1; srel = (size_t)(blk - 768) * 1024;  drel = 786432 + srel; }
    else if (blk < 2048) { src = w2; srel = (size_t)(blk - 1024) * 1024; drel = 1048576 + srel; }
    else                 { src = w3; srel = (size_t)(blk - 2048) * 1024; drel = 2097152 + srel; }
    int i = threadIdx.x * 4;
    float4 v = *(const float4*)(src + srel + i);
    bf16* d = dst + drel + i;
    d[0] = (bf16)v.x; d[1] = (bf16)v.y; d[2] = (bf16)v.z; d[3] = (bf16)v.w;
}

// ---------------- bias+mask table: bt[type][head][q][64]  (k-pad = -1e9)
__global__ __launch_bounds__(64) void bias_table_kernel(
    const float* __restrict__ rpb, float* __restrict__ bt)
{
    int tq = blockIdx.x;                  // [0, 4*16*49)
    int type = tq / 784, r = tq - type * 784;
    int head = r / 49, q = r - head * 49;
    int k = threadIdx.x;
    float v;
    if (k < 49) {
        int yq = q / 7, xq = q - yq * 7;
        int yk = k / 7, xk = k - yk * 7;
        int ridx = (yq - yk + 6) * 13 + (xq - xk + 6);
        v = rpb[ridx * 16 + head];
        int th = type >> 1, tw = type & 1;
        int qid = 3 * (th ? (yq < 4 ? 1 : 2) : 0) + (tw ? (xq < 4 ? 1 : 2) : 0);
        int kid = 3 * (th ? (yk < 4 ? 1 : 2) : 0) + (tw ? (xk < 4 ? 1 : 2) : 0);
        if (qid != kid) v -= 100.f;
    } else {
        v = -1e9f;
    }
    bt[(size_t)tq * 64 + k] = v;
}

// ---------------- LN1 + cyclic shift + window partition -> h (window-token order, bf16)
__global__ __launch_bounds__(256) void ln1_window_kernel(
    const float* __restrict__ x, const float* __restrict__ g, const float* __restrict__ bta,
    bf16* __restrict__ h)
{
    int t = blockIdx.x;                 // window-token index
    int win = t / 49, n = t - win * 49;
    int bi = win >> 6, nw = win & 63;
    int wh = nw >> 3, ww = nw & 7;
    int ny = n / 7, nx = n - ny * 7;
    int r = wh * 7 + ny + 3; if (r >= 56) r -= 56;   // roll(-3)
    int c = ww * 7 + nx + 3; if (c >= 56) c -= 56;
    const float* xr = x + ((size_t)bi * 3136 + r * 56 + c) * 512;
    int tid = threadIdx.x;
    float v0 = xr[tid];
    float v1 = xr[tid + 256];
    float s = v0 + v1, ss = v0 * v0 + v1 * v1;
#pragma unroll
    for (int o = 32; o; o >>= 1) { s += __shfl_down(s, o, 64); ss += __shfl_down(ss, o, 64); }
    __shared__ float red[8];
    int wave = tid >> 6, lane = tid & 63;
    if (lane == 0) { red[wave] = s; red[4 + wave] = ss; }
    __syncthreads();
    float S = red[0] + red[1] + red[2] + red[3];
    float SS = red[4] + red[5] + red[6] + red[7];
    float mean = S * (1.f / 512.f);
    float var = SS * (1.f / 512.f) - mean * mean;
    float rstd = rsqrtf(var + 1e-5f);
    bf16* hr = h + (size_t)t * 512;
    hr[tid] = (bf16)((v0 - mean) * rstd * g[tid] + bta[tid]);
    hr[tid + 256] = (bf16)((v1 - mean) * rstd * g[tid + 256] + bta[tid + 256]);
}

// ---------------- LN2 (natural token order), x1 (fp32 or bf16) -> bf16 out
template <int X1BF>
__global__ __launch_bounds__(256) void ln2_kernel(
    const void* __restrict__ x1, const float* __restrict__ g,
    const float* __restrict__ bta, bf16* __restrict__ outp)
{
    int t = blockIdx.x;
    int tid = threadIdx.x;
    float v0, v1;
    if constexpr (X1BF) {
        const bf16* xr = (const bf16*)x1 + (size_t)t * 512;
        v0 = (float)xr[tid]; v1 = (float)xr[tid + 256];
    } else {
        const float* xr = (const float*)x1 + (size_t)t * 512;
        v0 = xr[tid]; v1 = xr[tid + 256];
    }
    float s = v0 + v1, ss = v0 * v0 + v1 * v1;
#pragma unroll
    for (int o = 32; o; o >>= 1) { s += __shfl_down(s, o, 64); ss += __shfl_down(ss, o, 64); }
    __shared__ float red[8];
    int wave = tid >> 6, lane = tid & 63;
    if (lane == 0) { red[wave] = s; red[4 + wave] = ss; }
    __syncthreads();
    float S = red[0] + red[1] + red[2] + red[3];
    float SS = red[4] + red[5] + red[6] + red[7];
    float mean = S * (1.f / 512.f);
    float var = SS * (1.f / 512.f) - mean * mean;
    float rstd = rsqrtf(var + 1e-5f);
    bf16* hr = outp + (size_t)t * 512;
    hr[tid] = (bf16)((v0 - mean) * rstd * g[tid] + bta[tid]);
    hr[tid + 256] = (bf16)((v1 - mean) * rstd * g[tid + 256] + bta[tid + 256]);
}

// ---------------- 128x128 MFMA GEMM, BK=64 single-buffer, C^T registers (r8 winner, exact).
// LDS [128][64] row-XOR swizzle; global_load_lds staging; launch_bounds(256,4)
// (NOTE: 2nd arg = min waves/SIMD; 5 caused acc spill -> 916MB scratch traffic in r11)
template <int MODE, int K, int X1BF>
__global__ __launch_bounds__(256, 4) void gemm128b_kernel(
    const bf16* __restrict__ A, const bf16* __restrict__ Wt, const float* __restrict__ bias,
    void* __restrict__ outp, const void* __restrict__ extra, int N)
{
    __shared__ bf16 As[128][64];
    __shared__ bf16 Ws[128][64];
    constexpr int NT = K / 64;
    int gx = gridDim.x;
    int lin = blockIdx.y * gx + blockIdx.x;
    int q8 = (gx * gridDim.y) >> 3;          // grids divisible by 8
    int lin2 = (lin & 7) * q8 + (lin >> 3);
    int bn = lin2 % gx, bm = lin2 / gx;
    int tid = threadIdx.x;
    int w = tid >> 6, lane = tid & 63;
    int wm = w >> 1, wn = w & 1;
    int fr = lane & 15, fq = lane >> 4;
    int srow = lane >> 3;                     // 0..7 within 8-row chunk
    int scol = ((lane & 7) ^ srow) * 8;       // pre-swizzled source slot
    const bf16* gA = A + (size_t)(bm * 128 + w * 32 + srow) * K + scol;
    const bf16* gB = Wt + (size_t)(bn * 128 + w * 32 + srow) * K + scol;

    f32x4 acc[4][4];
    f32x4 z = {0.f, 0.f, 0.f, 0.f};
#pragma unroll
    for (int mf = 0; mf < 4; mf++)
#pragma unroll
        for (int nf = 0; nf < 4; nf++) acc[mf][nf] = z;

    for (int kt = 0; kt < NT; ++kt) {
        if (kt) {
            asm volatile("s_waitcnt lgkmcnt(0)" ::: "memory");
            asm volatile("s_barrier" ::: "memory");      // readers of prev tile done
        }
#pragma unroll
        for (int i = 0; i < 4; i++)
            GLD16(&As[w * 32 + i * 8][0], gA + (size_t)(i * 8) * K + kt * 64);
#pragma unroll
        for (int i = 0; i < 4; i++)
            GLD16(&Ws[w * 32 + i * 8][0], gB + (size_t)(i * 8) * K + kt * 64);
        asm volatile("s_waitcnt vmcnt(0)" ::: "memory");
        asm volatile("s_barrier" ::: "memory");
#pragma unroll
        for (int kh = 0; kh < 2; kh++) {
            bf16x8 aF[4], bF[4];
            int c = kh * 4 + fq;
#pragma unroll
            for (int f = 0; f < 4; f++) {
                aF[f] = *(const bf16x8*)&As[wm * 64 + f * 16 + fr][(c ^ (fr & 7)) * 8];
                bF[f] = *(const bf16x8*)&Ws[wn * 64 + f * 16 + fr][(c ^ (fr & 7)) * 8];
            }
#pragma unroll
            for (int mf = 0; mf < 4; mf++)
#pragma unroll
                for (int nf = 0; nf < 4; nf++)
                    acc[mf][nf] = __builtin_amdgcn_mfma_f32_16x16x32_bf16(bF[nf], aF[mf], acc[mf][nf], 0, 0, 0);
        }
    }

    // epilogue: per (mf, nf) one vector of 4 consecutive cols at row (..+fr)
#pragma unroll
    for (int mf = 0; mf < 4; mf++) {
        int row = bm * 128 + wm * 64 + mf * 16 + fr;
        size_t rowbase;
        if constexpr (MODE == 2) {
            int win = row / 49, n = row - win * 49;
            int bi = win >> 6, nw = win & 63;
            int wh = nw >> 3, wwi = nw & 7;
            int ny = n / 7, nx = n - ny * 7;
            int rr = wh * 7 + ny + 3; if (rr >= 56) rr -= 56;
            int cc = wwi * 7 + nx + 3; if (cc >= 56) cc -= 56;
            rowbase = ((size_t)bi * 3136 + rr * 56 + cc) * 512;
        } else {
            rowbase = (size_t)row * (MODE == 3 ? 512 : N);
        }
#pragma unroll
        for (int nf = 0; nf < 4; nf++) {
            int colb = bn * 128 + wn * 64 + nf * 16 + fq * 4;
            float4 b4 = *(const float4*)(bias + colb);
            float v0 = acc[mf][nf][0] + b4.x;
            float v1 = acc[mf][nf][1] + b4.y;
            float v2 = acc[mf][nf][2] + b4.z;
            float v3 = acc[mf][nf][3] + b4.w;
            size_t dst = rowbase + colb;
            if constexpr (MODE == 0) {
                bf16x4 t = {(bf16)v0, (bf16)v1, (bf16)v2, (bf16)v3};
                *(bf16x4*)((bf16*)outp + dst) = t;
            } else if constexpr (MODE == 1) {
                v0 = 0.5f * v0 * (1.f + erff(v0 * 0.70710678118654752f));
                v1 = 0.5f * v1 * (1.f + erff(v1 * 0.70710678118654752f));
                v2 = 0.5f * v2 * (1.f + erff(v2 * 0.70710678118654752f));
                v3 = 0.5f * v3 * (1.f + erff(v3 * 0.70710678118654752f));
                bf16x4 t = {(bf16)v0, (bf16)v1, (bf16)v2, (bf16)v3};
                *(bf16x4*)((bf16*)outp + dst) = t;
            } else if constexpr (MODE == 2) {
                float4 e = *(const float4*)((const float*)extra + dst);
                v0 += e.x; v1 += e.y; v2 += e.z; v3 += e.w;
                if constexpr (X1BF) {
                    bf16x4 t = {(bf16)v0, (bf16)v1, (bf16)v2, (bf16)v3};
                    *(bf16x4*)((bf16*)outp + dst) = t;
                } else {
                    float4 t = {v0, v1, v2, v3};
                    *(float4*)((float*)outp + dst) = t;
                }
            } else {
                if constexpr (X1BF) {
                    bf16x4 e = *(const bf16x4*)((const bf16*)extra + dst);
                    v0 += (float)e[0]; v1 += (float)e[1]; v2 += (float)e[2]; v3 += (float)e[3];
                } else {
                    float4 e = *(const float4*)((const float*)extra + dst);
                    v0 += e.x; v1 += e.y; v2 += e.z; v3 += e.w;
                }
                float4 t = {v0, v1, v2, v3};
                *(float4*)((float*)outp + dst) = t;
            }
        }
    }
}

// ---------------- MFMA attention: one wave per (window, head). N=49 (pad 64), hd=32.
// Independent 1-wave blocks -> setprio(1) around MFMA clusters (m191 regime).
__global__ __launch_bounds__(64) void attn_mfma_kernel(
    const bf16* __restrict__ qkv, const float* __restrict__ bt, bf16* __restrict__ outp)
{
    int wid0 = blockIdx.x;
    int wid = (wid0 & 7) * 2048 + (wid0 >> 3);   // XCD-contiguous windows
    int win = wid >> 4, head = wid & 15;
    int nw = win & 63;
    int type = ((nw >> 3) == 7 ? 2 : 0) + ((nw & 7) == 7 ? 1 : 0);
    int lane = threadIdx.x;
    int fr = lane & 15, fq = lane >> 4;
    __shared__ bf16 Vt[32][72];
    __shared__ bf16 Ps[64][72];
    const bf16* base = qkv + (size_t)win * 49 * 1536;

    uint4 z4 = {0, 0, 0, 0};
#pragma unroll
    for (int c = lane; c < 288; c += 64) ((uint4*)Vt)[c] = z4;
    __syncthreads();
    for (int c = lane; c < 1568; c += 64) {
        int tok = c >> 5, d = c & 31;
        Vt[d][tok] = base[(size_t)tok * 1536 + 1024 + head * 32 + d];
    }
    bf16x8 qf[4], kf[4];
#pragma unroll
    for (int i = 0; i < 4; i++) {
        int tq = i * 16 + fr; if (tq > 48) tq = 48;
        qf[i] = *(const bf16x8*)(base + (size_t)tq * 1536 + head * 32 + fq * 8);
        kf[i] = *(const bf16x8*)(base + (size_t)tq * 1536 + 512 + head * 32 + fq * 8);
    }
    f32x4 z = {0.f, 0.f, 0.f, 0.f};
    f32x4 st[4][4];
    __builtin_amdgcn_s_setprio(1);
#pragma unroll
    for (int mi = 0; mi < 4; mi++)
#pragma unroll
        for (int ni = 0; ni < 4; ni++)
            st[mi][ni] = __builtin_amdgcn_mfma_f32_16x16x32_bf16(kf[mi], qf[ni], z, 0, 0, 0);
    __builtin_amdgcn_s_setprio(0);
    __syncthreads();

    const float* btb = bt + (size_t)(type * 16 + head) * 49 * 64;
    float p[4][4][4];
    float inv[4];
#pragma unroll
    for (int ni = 0; ni < 4; ni++) {
        int q = ni * 16 + fr; if (q > 48) q = 48;
        const float* btr = btb + q * 64;
        float m = -1e30f;
#pragma unroll
        for (int mi = 0; mi < 4; mi++) {
            float4 bv = *(const float4*)(btr + mi * 16 + fq * 4);
#pragma unroll
            for (int r = 0; r < 4; r++) {
                float s = st[mi][ni][r] * 0.17677669529663689f + (&bv.x)[r];
                p[mi][ni][r] = s;
                m = fmaxf(m, s);
            }
        }
        m = fmaxf(m, __shfl_xor(m, 16));
        m = fmaxf(m, __shfl_xor(m, 32));
        float sum = 0.f;
#pragma unroll
        for (int mi = 0; mi < 4; mi++)
#pragma unroll
            for (int r = 0; r < 4; r++) {
                float e = __expf(p[mi][ni][r] - m);
                p[mi][ni][r] = e;
                sum += e;
            }
        sum += __shfl_xor(sum, 16);
        sum += __shfl_xor(sum, 32);
        inv[ni] = 1.f / sum;
    }
#pragma unroll
    for (int mi = 0; mi < 4; mi++)
#pragma unroll
        for (int ni = 0; ni < 4; ni++) {
            bf16x4 t;
            t[0] = (bf16)p[mi][ni][0]; t[1] = (bf16)p[mi][ni][1];
            t[2] = (bf16)p[mi][ni][2]; t[3] = (bf16)p[mi][ni][3];
            *(bf16x4*)&Ps[ni * 16 + fr][mi * 16 + fq * 4] = t;
        }
    __syncthreads();
    f32x4 o[2][4];
#pragma unroll
    for (int mi = 0; mi < 2; mi++)
#pragma unroll
        for (int ni = 0; ni < 4; ni++) o[mi][ni] = z;
    __builtin_amdgcn_s_setprio(1);
#pragma unroll
    for (int kt = 0; kt < 2; kt++) {
        bf16x8 a0 = *(const bf16x8*)&Vt[fr][kt * 32 + fq * 8];
        bf16x8 a1 = *(const bf16x8*)&Vt[16 + fr][kt * 32 + fq * 8];
#pragma unroll
        for (int ni = 0; ni < 4; ni++) {
            bf16x8 b = *(const bf16x8*)&Ps[ni * 16 + fr][kt * 32 + fq * 8];
            o[0][ni] = __builtin_amdgcn_mfma_f32_16x16x32_bf16(a0, b, o[0][ni], 0, 0, 0);
            o[1][ni] = __builtin_amdgcn_mfma_f32_16x16x32_bf16(a1, b, o[1][ni], 0, 0, 0);
        }
    }
    __builtin_amdgcn_s_setprio(0);
#pragma unroll
    for (int ni = 0; ni < 4; ni++) {
        int q = ni * 16 + fr;
        if (q < 49) {
            bf16* orow = outp + (size_t)(win * 49 + q) * 512 + head * 32;
#pragma unroll
            for (int mi = 0; mi < 2; mi++)
#pragma unroll
                for (int r2 = 0; r2 < 2; r2++) {
                    bf16x2 t;
                    t[0] = (bf16)(o[mi][ni][2 * r2] * inv[ni]);
                    t[1] = (bf16)(o[mi][ni][2 * r2 + 1] * inv[ni]);
                    *(bf16x2*)(orow + mi * 16 + fq * 4 + 2 * r2) = t;
                }
        }
    }
}

extern "C" void kernel_launch(void* const* d_in, const int* in_sizes, int n_in,
                              void* d_out, int out_size, void* d_ws, size_t ws_size,
                              hipStream_t stream)
{
    const float* x      = (const float*)d_in[0];
    const float* n1g    = (const float*)d_in[1];
    const float* n1b    = (const float*)d_in[2];
    const float* qkv_w  = (const float*)d_in[3];
    const float* qkv_b  = (const float*)d_in[4];
    const float* proj_w = (const float*)d_in[5];
    const float* proj_b = (const float*)d_in[6];
    const float* rpb    = (const float*)d_in[7];
    const float* n2g    = (const float*)d_in[8];
    const float* n2b    = (const float*)d_in[9];
    const float* fc1_w  = (const float*)d_in[10];
    const float* fc1_b  = (const float*)d_in[11];
    const float* fc2_w  = (const float*)d_in[12];
    const float* fc2_b  = (const float*)d_in[13];

    char* ws = (char*)d_ws;
    // layout (bytes):
    //   [0, 154140672)            qkv bf16                       } hid (50176x2048 bf16)
    //   [154140672, 205520896)    h bf16 -> bt fp32 after qkvGEMM}   overlays
    //   [205520896, 256901120)    attn_out bf16 -> ln2h bf16
    //   [256901120, 263192576)    weights bf16
    //   [263192576, 314572800)    x1 bf16 (only if ws_size permits)
    bf16* qkv  = (bf16*)ws;
    bf16* h    = (bf16*)(ws + 154140672ull);
    float* bt  = (float*)(ws + 154140672ull);
    bf16* ao   = (bf16*)(ws + 205520896ull);
    bf16* wbuf = (bf16*)(ws + 256901120ull);
    bf16* hid  = (bf16*)ws;
    bf16* ln2h = ao;
    bf16* wq  = wbuf;
    bf16* wp  = wbuf + 786432;
    bf16* wf1 = wbuf + 1048576;
    bf16* wf2 = wbuf + 2097152;

    bool xb = (ws_size >= 314572800ull);
    void* x1 = xb ? (void*)(ws + 263192576ull) : (void*)d_out;

    convert_w_kernel<<<3072, 256, 0, stream>>>(qkv_w, proj_w, fc1_w, fc2_w, wbuf);
    ln1_window_kernel<<<M_TOK, 256, 0, stream>>>(x, n1g, n1b, h);
    gemm128b_kernel<0, 512, 0><<<dim3(12, 392), 256, 0, stream>>>(h, wq, qkv_b, qkv, nullptr, 1536);
    bias_table_kernel<<<3136, 64, 0, stream>>>(rpb, bt);
    attn_mfma_kernel<<<16384, 64, 0, stream>>>(qkv, bt, ao);
    if (xb) {
        gemm128b_kernel<2, 512, 1><<<dim3(4, 392), 256, 0, stream>>>(ao, wp, proj_b, x1, x, 512);
        ln2_kernel<1><<<M_TOK, 256, 0, stream>>>(x1, n2g, n2b, ln2h);
        gemm128b_kernel<1, 512, 1><<<dim3(16, 392), 256, 0, stream>>>(ln2h, wf1, fc1_b, hid, nullptr, 2048);
        gemm128b_kernel<3, 2048, 1><<<dim3(4, 392), 256, 0, stream>>>(hid, wf2, fc2_b, d_out, x1, 512);
    } else {
        gemm128b_kernel<2, 512, 0><<<dim3(4, 392), 256, 0, stream>>>(ao, wp, proj_b, x1, x, 512);
        ln2_kernel<0><<<M_TOK, 256, 0, stream>>>(x1, n2g, n2b, ln2h);
        gemm128b_kernel<1, 512, 0><<<dim3(16, 392), 256, 0, stream>>>(ln2h, wf1, fc1_b, hid, nullptr, 2048);
        gemm128b_kernel<3, 2048, 0><<<dim3(4, 392), 256, 0, stream>>>(hid, wf2, fc2_b, d_out, x1, 512);
    }
}